// Round 1
// baseline (248.007 us; speedup 1.0000x reference)
//
#include <hip/hip_runtime.h>
#include <math.h>

#define IMG_H 512
#define IMG_W 512
#define HWSZ (IMG_H * IMG_W)

// ---------------------------------------------------------------------------
// Kernel 1: per-image RGB-uv histogram.
// One block per image, 1024 threads = one thread per downsampled pixel.
// Writes hist as [B][3072] row-major (f32) into workspace.
// ---------------------------------------------------------------------------
__global__ __launch_bounds__(1024) void hist_kernel(const float* __restrict__ img,
                                                    float* __restrict__ hist)
{
    const int b   = blockIdx.x;
    const int tid = threadIdx.x;

    __shared__ float hh[3][1024];
    __shared__ float red[17];

    hh[0][tid] = 0.f;
    hh[1][tid] = 0.f;
    hh[2][tid] = 0.f;
    __syncthreads();

    // nearest-downsample: src index = 16*dst (512/32 == 16 exactly)
    const int py  = tid >> 5;
    const int pxi = tid & 31;
    const size_t base = (size_t)b * 3 * HWSZ + (size_t)(py * 16) * IMG_W + (size_t)(pxi * 16);

    const float r  = img[base];
    const float g  = img[base + HWSZ];
    const float bl = img[base + 2 * HWSZ];

    const bool valid = (r > 0.f) && (g > 0.f) && (bl > 0.f);

    // constants exactly as the reference (f64 arithmetic, then cast to f32)
    const float LOc = (float)(-3.2 - (6.4 / 256.0) * 0.5);
    const float HIc = (float)( 3.2 - (6.4 / 256.0) * 0.5);
    const float BWc = (float)(((3.2 - (6.4 / 256.0) * 0.5) - (-3.2 - (6.4 / 256.0) * 0.5)) / 32.0);

    if (valid) {
        const float w  = sqrtf(r * r + g * g + bl * bl);
        const float lr = logf(r);
        const float lg = logf(g);
        const float lb = logf(bl);

        // i=0: Iu = l0 - l2, Iv = l0 - l1
        // i=1: Iu = l1 - l2, Iv = l1 - l0
        // i=2: Iu = l2 - l1, Iv = l2 - l0
        float us[3] = { lr - lb, lg - lb, lb - lg };
        float vs[3] = { lr - lg, lg - lr, lb - lr };

        #pragma unroll
        for (int i = 0; i < 3; ++i) {
            const float U = us[i];
            const float V = vs[i];
            if (U >= LOc && U <= HIc && V >= LOc && V <= HIc) {
                int iu = (int)floorf((U - LOc) / BWc); iu = iu < 31 ? iu : 31;
                int iv = (int)floorf((V - LOc) / BWc); iv = iv < 31 ? iv : 31;
                atomicAdd(&hh[i][iu * 32 + iv], w);
            }
        }
    }
    __syncthreads();

    // per-channel sum + sqrt-normalize
    float inv[3];
    #pragma unroll
    for (int i = 0; i < 3; ++i) {
        float v = hh[i][tid];
        #pragma unroll
        for (int off = 32; off; off >>= 1) v += __shfl_down(v, off);
        if ((tid & 63) == 0) red[tid >> 6] = v;
        __syncthreads();
        if (tid == 0) {
            float s = 0.f;
            #pragma unroll
            for (int j = 0; j < 16; ++j) s += red[j];
            red[16] = 1.0f / s;
        }
        __syncthreads();
        inv[i] = red[16];
        __syncthreads();   // red[] reused next iteration
    }

    float* hrow = hist + (size_t)b * 3072;
    #pragma unroll
    for (int i = 0; i < 3; ++i)
        hrow[i * 1024 + tid] = sqrtf(hh[i][tid] * inv[i]);
}

// ---------------------------------------------------------------------------
// Kernels 2-4: y[b][o] = relu(sum_k x[b][k] * W[o][k] + bias[o])
// One wave per output feature o; 64 lanes split K (float4 each -> coalesced
// 1 KiB weight-row load per wave per step); 32 accumulators = all batch rows.
// x rows are tiny (<= 384 KB total) and L1/L2-resident.
// ---------------------------------------------------------------------------
template <int K>
__global__ __launch_bounds__(256) void linear_relu(const float* __restrict__ x,    // [32][K]
                                                   const float* __restrict__ W,    // [N][K]
                                                   const float* __restrict__ bias, // [N]
                                                   float* __restrict__ y,          // [32][N]
                                                   int N)
{
    const int o    = (blockIdx.x * 256 + threadIdx.x) >> 6;  // one wave per o
    const int lane = threadIdx.x & 63;

    const float* wrow = W + (size_t)o * K;

    float acc[32];
    #pragma unroll
    for (int b = 0; b < 32; ++b) acc[b] = 0.f;

    // K is a multiple of 256 = 64 lanes * 4
    #pragma unroll 2
    for (int kc = 0; kc < K; kc += 256) {
        const int k = kc + lane * 4;
        const float4 w4 = *reinterpret_cast<const float4*>(wrow + k);
        #pragma unroll
        for (int b = 0; b < 32; ++b) {
            const float4 x4 = *reinterpret_cast<const float4*>(x + b * K + k);
            acc[b] += w4.x * x4.x + w4.y * x4.y + w4.z * x4.z + w4.w * x4.w;
        }
    }

    #pragma unroll
    for (int b = 0; b < 32; ++b) {
        float v = acc[b];
        #pragma unroll
        for (int off = 32; off; off >>= 1) v += __shfl_down(v, off);
        if (lane == 0) {
            v += bias[o];
            y[b * N + o] = v > 0.f ? v : 0.f;
        }
    }
}

// ---------------------------------------------------------------------------
extern "C" void kernel_launch(void* const* d_in, const int* in_sizes, int n_in,
                              void* d_out, int out_size, void* d_ws, size_t ws_size,
                              hipStream_t stream)
{
    const float* img = (const float*)d_in[0];
    const float* W1  = (const float*)d_in[1];
    const float* b1  = (const float*)d_in[2];
    const float* W2  = (const float*)d_in[3];
    const float* b2  = (const float*)d_in[4];
    const float* W3  = (const float*)d_in[5];
    const float* b3  = (const float*)d_in[6];
    float* out = (float*)d_out;

    const int B = in_sizes[0] / (3 * HWSZ);   // 32

    float* hist = (float*)d_ws;               // [B][3072]
    float* x1   = hist + (size_t)B * 3072;    // [B][1024]
    float* x2   = x1   + (size_t)B * 1024;    // [B][512]

    hist_kernel<<<B, 1024, 0, stream>>>(img, hist);
    linear_relu<3072><<<1024 / 4, 256, 0, stream>>>(hist, W1, b1, x1, 1024);
    linear_relu<1024><<< 512 / 4, 256, 0, stream>>>(x1,   W2, b2, x2, 512);
    linear_relu< 512><<< 256 / 4, 256, 0, stream>>>(x2,   W3, b3, out, 256);
}

// Round 2
// 189.543 us; speedup vs baseline: 1.3085x; 1.3085x over previous
//
#include <hip/hip_runtime.h>
#include <math.h>

#define IMG_H 512
#define IMG_W 512
#define HWSZ (IMG_H * IMG_W)
#define BATCH 32

// ---------------------------------------------------------------------------
// Kernel 1: partial histograms. 4 blocks per image, 256 threads = 1 pixel each.
// hp[img*4+blk][3072] raw weighted bin sums.
// ---------------------------------------------------------------------------
__global__ __launch_bounds__(256) void hist_part_k(const float* __restrict__ img,
                                                   float* __restrict__ hp)
{
    const int img_i = blockIdx.x >> 2;
    const int blk   = blockIdx.x & 3;
    const int tid   = threadIdx.x;

    __shared__ float hh[3072];
    for (int i = tid; i < 3072; i += 256) hh[i] = 0.f;
    __syncthreads();

    const int p  = blk * 256 + tid;          // downsampled pixel id 0..1023
    const int py = p >> 5;
    const int px = p & 31;
    const size_t base = (size_t)img_i * 3 * HWSZ + (size_t)(py * 16) * IMG_W + (size_t)(px * 16);

    const float r  = img[base];
    const float g  = img[base + HWSZ];
    const float bl = img[base + 2 * HWSZ];

    const bool valid = (r > 0.f) && (g > 0.f) && (bl > 0.f);

    const float LOc = (float)(-3.2 - (6.4 / 256.0) * 0.5);
    const float HIc = (float)( 3.2 - (6.4 / 256.0) * 0.5);
    const float BWc = (float)(((3.2 - (6.4 / 256.0) * 0.5) - (-3.2 - (6.4 / 256.0) * 0.5)) / 32.0);

    if (valid) {
        const float w  = sqrtf(r * r + g * g + bl * bl);
        const float lr = logf(r);
        const float lg = logf(g);
        const float lb = logf(bl);

        float us[3] = { lr - lb, lg - lb, lb - lg };
        float vs[3] = { lr - lg, lg - lr, lb - lr };

        #pragma unroll
        for (int i = 0; i < 3; ++i) {
            const float U = us[i];
            const float V = vs[i];
            if (U >= LOc && U <= HIc && V >= LOc && V <= HIc) {
                int iu = (int)floorf((U - LOc) / BWc); iu = iu < 31 ? iu : 31;
                int iv = (int)floorf((V - LOc) / BWc); iv = iv < 31 ? iv : 31;
                atomicAdd(&hh[i * 1024 + iu * 32 + iv], w);
            }
        }
    }
    __syncthreads();

    float* outp = hp + (size_t)blockIdx.x * 3072;
    for (int i = tid; i < 3072; i += 256) outp[i] = hh[i];
}

// ---------------------------------------------------------------------------
// Kernel 2: per-image normalize + sqrt, write TRANSPOSED histT[3072][32].
// One block (1024 threads) per image.
// ---------------------------------------------------------------------------
__global__ __launch_bounds__(1024) void hist_norm_k(const float* __restrict__ hp,
                                                    float* __restrict__ histT)
{
    const int img_i = blockIdx.x;
    const int tid   = threadIdx.x;
    const int wid   = tid >> 6;
    const int lane  = tid & 63;

    __shared__ float red[17];
    const float* base = hp + (size_t)img_i * 4 * 3072;

    #pragma unroll
    for (int c = 0; c < 3; ++c) {
        const int idx = c * 1024 + tid;
        float v = base[idx] + base[3072 + idx] + base[2 * 3072 + idx] + base[3 * 3072 + idx];

        float t = v;
        #pragma unroll
        for (int off = 32; off; off >>= 1) t += __shfl_down(t, off);
        if (lane == 0) red[wid] = t;
        __syncthreads();
        if (tid == 0) {
            float s = 0.f;
            #pragma unroll
            for (int j = 0; j < 16; ++j) s += red[j];
            red[16] = s;
        }
        __syncthreads();
        const float s = red[16];
        histT[(size_t)(c * 1024 + tid) * BATCH + img_i] = sqrtf(v / s);
        __syncthreads();   // red reused next channel
    }
}

// ---------------------------------------------------------------------------
// GEMM partial kernel: part[s][o][b] = sum_{k in chunk s} xT[k][b] * W[o][k]
// Wave = 8 outputs x 32 batches x chunk C. lane = (khalf, b):
//   x load  : xT[(k0+kk)*32 + lane]        -> one coalesced 256B segment
//   w load  : W[(o0+j)*K + k0+kk+khalf]    -> 2-address broadcast
// Each lane's acc is complete over its k-subslice; one shfl_xor(32) finishes it.
// ---------------------------------------------------------------------------
template <int K, int N, int S>
__global__ __launch_bounds__(256) void gemm_part_k(const float* __restrict__ xT,
                                                   const float* __restrict__ W,
                                                   float* __restrict__ part)
{
    constexpr int C  = K / S;
    constexpr int NG = N / 8;

    const int wave = (blockIdx.x * 256 + threadIdx.x) >> 6;
    const int lane = threadIdx.x & 63;
    const int og   = wave % NG;
    const int s    = wave / NG;
    const int o0   = og * 8;
    const int k0   = s * C;
    const int khalf = lane >> 5;
    const int b     = lane & 31;

    float acc[8] = {0.f, 0.f, 0.f, 0.f, 0.f, 0.f, 0.f, 0.f};

    const float* xp = xT + (size_t)k0 * BATCH + lane;

    #pragma unroll 4
    for (int kk = 0; kk < C; kk += 2) {
        const float xv = xp[kk * BATCH];
        const int k = k0 + kk + khalf;
        #pragma unroll
        for (int j = 0; j < 8; ++j)
            acc[j] += xv * W[(o0 + j) * K + k];
    }

    #pragma unroll
    for (int j = 0; j < 8; ++j)
        acc[j] += __shfl_xor(acc[j], 32);

    if (khalf == 0) {
        float* pp = part + ((size_t)s * N + o0) * BATCH + b;
        #pragma unroll
        for (int j = 0; j < 8; ++j)
            pp[j * BATCH] = acc[j];
    }
}

// ---------------------------------------------------------------------------
// Reduce: y[o][b] = relu(bias[o] + sum_s part[s][o][b]); LAST writes [b][o].
// ---------------------------------------------------------------------------
template <int N, int S, bool LAST>
__global__ __launch_bounds__(256) void reduce_bias_relu_k(const float* __restrict__ part,
                                                          const float* __restrict__ bias,
                                                          float* __restrict__ out)
{
    const int t = blockIdx.x * 256 + threadIdx.x;   // t in [0, N*32)
    float s = 0.f;
    #pragma unroll
    for (int i = 0; i < S; ++i)
        s += part[(size_t)i * N * BATCH + t];

    const int o = t >> 5;
    const int b = t & 31;
    s += bias[o];
    s = fmaxf(s, 0.f);
    if (LAST)
        out[b * N + o] = s;
    else
        out[t] = s;
}

// ---------------------------------------------------------------------------
extern "C" void kernel_launch(void* const* d_in, const int* in_sizes, int n_in,
                              void* d_out, int out_size, void* d_ws, size_t ws_size,
                              hipStream_t stream)
{
    const float* img = (const float*)d_in[0];
    const float* W1  = (const float*)d_in[1];
    const float* b1  = (const float*)d_in[2];
    const float* W2  = (const float*)d_in[3];
    const float* b2  = (const float*)d_in[4];
    const float* W3  = (const float*)d_in[5];
    const float* b3  = (const float*)d_in[6];
    float* out = (float*)d_out;

    float* ws = (float*)d_ws;
    float* histT   = ws;                    // [3072][32]
    float* x1T     = histT + 3072 * BATCH;  // [1024][32]
    float* x2T     = x1T   + 1024 * BATCH;  // [512][32]
    float* scratch = x2T   + 512 * BATCH;   // max(hist partials 393216, L1 partials 524288) floats

    // hist partials: [32*4][3072]; GEMM partials: [S][N][32] (aliased, sequential use)
    hist_part_k<<<BATCH * 4, 256, 0, stream>>>(img, scratch);
    hist_norm_k<<<BATCH, 1024, 0, stream>>>(scratch, histT);

    // L1: 3072 -> 1024
    gemm_part_k<3072, 1024, 16><<<(1024 / 8) * 16 / 4, 256, 0, stream>>>(histT, W1, scratch);
    reduce_bias_relu_k<1024, 16, false><<<1024 * BATCH / 256, 256, 0, stream>>>(scratch, b1, x1T);

    // L2: 1024 -> 512
    gemm_part_k<1024, 512, 16><<<(512 / 8) * 16 / 4, 256, 0, stream>>>(x1T, W2, scratch);
    reduce_bias_relu_k<512, 16, false><<<512 * BATCH / 256, 256, 0, stream>>>(scratch, b2, x2T);

    // L3: 512 -> 256
    gemm_part_k<512, 256, 16><<<(256 / 8) * 16 / 4, 256, 0, stream>>>(x2T, W3, scratch);
    reduce_bias_relu_k<256, 16, true><<<256 * BATCH / 256, 256, 0, stream>>>(scratch, b3, out);
}

// Round 3
// 188.628 us; speedup vs baseline: 1.3148x; 1.0048x over previous
//
#include <hip/hip_runtime.h>
#include <math.h>

#define IMG_H 512
#define IMG_W 512
#define HWSZ (IMG_H * IMG_W)
#define BATCH 32

// paired activation layout: element (k, b) lives at (k>>1)*64 + b*2 + (k&1)
// so one float2 per lane (b) covers k and k+1 -> 256B coalesced wave load.
__device__ __forceinline__ size_t xidx(int k, int b) {
    return (size_t)(k >> 1) * 64 + b * 2 + (k & 1);
}

// ---------------------------------------------------------------------------
// Kernel 1: blocks 0..127  = partial histograms (4 blocks/image, 1 px/thread)
//           blocks 128..351 = bias init of y1/y2/y3 (paired layout)
// ---------------------------------------------------------------------------
__global__ __launch_bounds__(256) void hist_part_k(const float* __restrict__ img,
                                                   float* __restrict__ hp,
                                                   const float* __restrict__ b1,
                                                   const float* __restrict__ b2,
                                                   const float* __restrict__ b3,
                                                   float* __restrict__ y1,
                                                   float* __restrict__ y2,
                                                   float* __restrict__ y3)
{
    if (blockIdx.x >= 128) {
        // bias init: t indexes the paired layout directly (contiguous stores)
        const int t = (blockIdx.x - 128) * 256 + threadIdx.x;
        if (t < 32768) {
            const int o = ((t >> 6) << 1) | (t & 1);
            y1[t] = b1[o];
        } else if (t < 49152) {
            const int u = t - 32768;
            const int o = ((u >> 6) << 1) | (u & 1);
            y2[u] = b2[o];
        } else {
            const int u = t - 49152;
            const int o = ((u >> 6) << 1) | (u & 1);
            y3[u] = b3[o];
        }
        return;
    }

    const int img_i = blockIdx.x >> 2;
    const int blk   = blockIdx.x & 3;
    const int tid   = threadIdx.x;

    __shared__ float hh[3072];
    for (int i = tid; i < 3072; i += 256) hh[i] = 0.f;
    __syncthreads();

    const int p  = blk * 256 + tid;          // downsampled pixel id 0..1023
    const int py = p >> 5;
    const int px = p & 31;
    const size_t base = (size_t)img_i * 3 * HWSZ + (size_t)(py * 16) * IMG_W + (size_t)(px * 16);

    const float r  = img[base];
    const float g  = img[base + HWSZ];
    const float bl = img[base + 2 * HWSZ];

    const bool valid = (r > 0.f) && (g > 0.f) && (bl > 0.f);

    const float LOc = (float)(-3.2 - (6.4 / 256.0) * 0.5);
    const float HIc = (float)( 3.2 - (6.4 / 256.0) * 0.5);
    const float BWc = (float)(((3.2 - (6.4 / 256.0) * 0.5) - (-3.2 - (6.4 / 256.0) * 0.5)) / 32.0);

    if (valid) {
        const float w  = sqrtf(r * r + g * g + bl * bl);
        const float lr = logf(r);
        const float lg = logf(g);
        const float lb = logf(bl);

        float us[3] = { lr - lb, lg - lb, lb - lg };
        float vs[3] = { lr - lg, lg - lr, lb - lr };

        #pragma unroll
        for (int i = 0; i < 3; ++i) {
            const float U = us[i];
            const float V = vs[i];
            if (U >= LOc && U <= HIc && V >= LOc && V <= HIc) {
                int iu = (int)floorf((U - LOc) / BWc); iu = iu < 31 ? iu : 31;
                int iv = (int)floorf((V - LOc) / BWc); iv = iv < 31 ? iv : 31;
                atomicAdd(&hh[i * 1024 + iu * 32 + iv], w);
            }
        }
    }
    __syncthreads();

    float* outp = hp + (size_t)blockIdx.x * 3072;
    for (int i = tid; i < 3072; i += 256) outp[i] = hh[i];
}

// ---------------------------------------------------------------------------
// Kernel 2: per-image normalize + sqrt, write paired-transposed histT.
// One block (1024 threads) per image.
// ---------------------------------------------------------------------------
__global__ __launch_bounds__(1024) void hist_norm_k(const float* __restrict__ hp,
                                                    float* __restrict__ histT)
{
    const int img_i = blockIdx.x;
    const int tid   = threadIdx.x;
    const int wid   = tid >> 6;
    const int lane  = tid & 63;

    __shared__ float red[17];
    const float* base = hp + (size_t)img_i * 4 * 3072;

    #pragma unroll
    for (int c = 0; c < 3; ++c) {
        const int idx = c * 1024 + tid;
        float v = base[idx] + base[3072 + idx] + base[2 * 3072 + idx] + base[3 * 3072 + idx];

        float t = v;
        #pragma unroll
        for (int off = 32; off; off >>= 1) t += __shfl_down(t, off);
        if (lane == 0) red[wid] = t;
        __syncthreads();
        if (tid == 0) {
            float s = 0.f;
            #pragma unroll
            for (int j = 0; j < 16; ++j) s += red[j];
            red[16] = s;
        }
        __syncthreads();
        const float s = red[16];
        histT[xidx(c * 1024 + tid, img_i)] = sqrtf(v / s);
        __syncthreads();   // red reused next channel
    }
}

// ---------------------------------------------------------------------------
// GEMM: y[o][b] += sum_{k in chunk} x[k][b] * W[o][k]   (atomic split-K)
// Wave = 8 outputs x 32 batches x chunk C. b = lane&31 (halves duplicate).
// W addresses are wave-uniform (readfirstlane) -> scalar s_load path.
// x loads: one float2 per lane = 256B coalesced per 2 k's.
// RELU applies relu to x on load (previous layer stored pre-activation).
// ---------------------------------------------------------------------------
template <int K, int N, int S, bool RELU>
__global__ __launch_bounds__(256) void gemm_atomic_k(const float* __restrict__ xT,
                                                     const float* __restrict__ W,
                                                     float* __restrict__ y)
{
    constexpr int C  = K / S;
    constexpr int NG = N / 8;

    const int wave = (blockIdx.x * 256 + threadIdx.x) >> 6;
    const int lane = threadIdx.x & 63;
    const int b    = lane & 31;
    const int o0   = __builtin_amdgcn_readfirstlane((wave % NG) * 8);
    const int k0   = __builtin_amdgcn_readfirstlane((wave / NG) * C);

    const float* Wr[8];
    #pragma unroll
    for (int j = 0; j < 8; ++j) Wr[j] = W + (size_t)(o0 + j) * K + k0;

    const float2* xp = reinterpret_cast<const float2*>(xT + (size_t)k0 * BATCH) + b;

    float acc[8] = {0.f, 0.f, 0.f, 0.f, 0.f, 0.f, 0.f, 0.f};

    #pragma unroll 4
    for (int kk2 = 0; kk2 < C / 2; ++kk2) {
        float2 v = xp[kk2 * BATCH];
        if (RELU) { v.x = fmaxf(v.x, 0.f); v.y = fmaxf(v.y, 0.f); }
        #pragma unroll
        for (int j = 0; j < 8; ++j) {
            acc[j] = fmaf(v.x, Wr[j][2 * kk2],     acc[j]);
            acc[j] = fmaf(v.y, Wr[j][2 * kk2 + 1], acc[j]);
        }
    }

    if (lane < 32) {
        #pragma unroll
        for (int j = 0; j < 8; ++j)
            atomicAdd(&y[xidx(o0 + j, b)], acc[j]);
    }
}

// ---------------------------------------------------------------------------
// Finish: out[b][o] = relu(y3[o][b])
// ---------------------------------------------------------------------------
__global__ __launch_bounds__(256) void finish_k(const float* __restrict__ y3,
                                                float* __restrict__ out)
{
    const int t = blockIdx.x * 256 + threadIdx.x;   // t = b*256 + o
    const int b = t >> 8;
    const int o = t & 255;
    out[t] = fmaxf(y3[xidx(o, b)], 0.f);
}

// ---------------------------------------------------------------------------
extern "C" void kernel_launch(void* const* d_in, const int* in_sizes, int n_in,
                              void* d_out, int out_size, void* d_ws, size_t ws_size,
                              hipStream_t stream)
{
    const float* img = (const float*)d_in[0];
    const float* W1  = (const float*)d_in[1];
    const float* b1  = (const float*)d_in[2];
    const float* W2  = (const float*)d_in[3];
    const float* b2  = (const float*)d_in[4];
    const float* W3  = (const float*)d_in[5];
    const float* b3  = (const float*)d_in[6];
    float* out = (float*)d_out;

    float* ws = (float*)d_ws;
    float* hp    = ws;                      // [128][3072] hist partials
    float* histT = hp    + 128 * 3072;      // [3072][32] paired
    float* y1    = histT + 3072 * BATCH;    // [1024][32] paired
    float* y2    = y1    + 1024 * BATCH;    // [512][32] paired
    float* y3    = y2    +  512 * BATCH;    // [256][32] paired

    // hist partials + bias init (fused)
    hist_part_k<<<128 + 224, 256, 0, stream>>>(img, hp, b1, b2, b3, y1, y2, y3);
    hist_norm_k<<<BATCH, 1024, 0, stream>>>(hp, histT);

    // L1: 3072 -> 1024   (2048 waves)
    gemm_atomic_k<3072, 1024, 16, false><<<512, 256, 0, stream>>>(histT, W1, y1);
    // L2: 1024 -> 512    (1024 waves)
    gemm_atomic_k<1024,  512, 16, true ><<<256, 256, 0, stream>>>(y1, W2, y2);
    // L3: 512 -> 256     (512 waves)
    gemm_atomic_k< 512,  256, 16, true ><<<128, 256, 0, stream>>>(y2, W3, y3);

    finish_k<<<32, 256, 0, stream>>>(y3, out);
}